// Round 3
// baseline (640.898 us; speedup 1.0000x reference)
//
#include <hip/hip_runtime.h>
#include <hip/hip_bf16.h>
#include <cstdint>
#include <cstddef>

#define N_NODES 50000
#define N_EDGES 800000
#define IN_CH 64
#define HID_CH 128
#define N_GRAPHS 64

typedef short s16x8 __attribute__((ext_vector_type(8)));
typedef float f32x4 __attribute__((ext_vector_type(4)));

__device__ __forceinline__ float bf2f(__hip_bfloat16 v) { return __bfloat162float(v); }

// flags[0]: 1 if float tensors are fp32, 0 if bf16
// flags[1]: 1 if int tensors are int64, 0 if int32
__global__ void detect_dtypes(const unsigned* __restrict__ xr,
                              const unsigned* __restrict__ eir,
                              int* __restrict__ flags) {
  __shared__ int cnt_plaus, cnt_odd_nz;
  if (threadIdx.x == 0) { cnt_plaus = 0; cnt_odd_nz = 0; }
  __syncthreads();
  int t = threadIdx.x;  // 256 threads
  {
    unsigned h = xr[t] & 0xffffu;          // even-index 16-bit half as bf16
    unsigned e = (h >> 7) & 0xffu;
    if (e == 0u || (e >= 90u && e <= 150u)) atomicAdd(&cnt_plaus, 1);
  }
  if (eir[2 * t + 1] != 0u) atomicAdd(&cnt_odd_nz, 1);  // int64 high halves all zero
  __syncthreads();
  if (t == 0) {
    flags[0] = (cnt_plaus < 160) ? 1 : 0;
    flags[1] = (cnt_odd_nz == 0) ? 1 : 0;
  }
}

__device__ __forceinline__ float load_f(const void* p, int i, int fp32) {
  return fp32 ? ((const float*)p)[i] : bf2f(((const __hip_bfloat16*)p)[i]);
}
__device__ __forceinline__ int load_id_clamped(const void* p, int i, int i64, int limit) {
  long long v = i64 ? ((const long long*)p)[i] : (long long)((const int*)p)[i];
  if (v < 0) v = 0;
  if (v >= limit) v = limit - 1;
  return (int)v;
}
__device__ __forceinline__ long long load_b(const void* p, int i, int i64) {
  return i64 ? ((const long long*)p)[i] : (long long)((const int*)p)[i];
}

// ---------------- canonicalization ----------------

__global__ void conv_x(const void* __restrict__ src, __hip_bfloat16* __restrict__ dst,
                       int n, const int* __restrict__ flags) {
  int i = blockIdx.x * blockDim.x + threadIdx.x;
  int f = flags[0];
  if (i < n) dst[i] = __float2bfloat16(load_f(src, i, f));
}

// 8 weight matrices, logical W[KD][128] -> WT[128][KD] bf16
__global__ void conv_wt(const void* s0, const void* s1, const void* s2, const void* s3,
                        const void* s4, const void* s5, const void* s6, const void* s7,
                        __hip_bfloat16* d0, __hip_bfloat16* d1, __hip_bfloat16* d2, __hip_bfloat16* d3,
                        __hip_bfloat16* d4, __hip_bfloat16* d5, __hip_bfloat16* d6, __hip_bfloat16* d7,
                        const int* __restrict__ flags) {
  const void* S[8] = {s0, s1, s2, s3, s4, s5, s6, s7};
  __hip_bfloat16* D[8] = {d0, d1, d2, d3, d4, d5, d6, d7};
  int i = blockIdx.x * blockDim.x + threadIdx.x;
  int f = flags[0];
  if (i >= 4 * 64 * 128 + 4 * 128 * 128) return;
  int m, r, KD;
  if (i < 4 * 64 * 128) { m = i >> 13; r = i & 8191; KD = 64; }
  else { int j = i - 4 * 64 * 128; m = 4 + (j >> 14); r = j & 16383; KD = 128; }
  int k = r >> 7, c = r & 127;
  D[m][c * KD + k] = __float2bfloat16(load_f(S[m], r, f));
}

// ---------------- CSR build ----------------

__global__ void init_ws(int* cnt, int* tmp, float* pooled) {
  int i = blockIdx.x * blockDim.x + threadIdx.x;
  if (i < N_NODES) { cnt[i] = 0; tmp[i] = 0; }
  if (i < N_GRAPHS * HID_CH) pooled[i] = 0.f;
}

__global__ void count_deg(const void* __restrict__ ei, int* __restrict__ cnt,
                          const int* __restrict__ flags) {
  int e = blockIdx.x * blockDim.x + threadIdx.x;
  int f = flags[1];
  if (e < N_EDGES) atomicAdd(&cnt[load_id_clamped(ei, N_EDGES + e, f, N_NODES)], 1);
}

__global__ __launch_bounds__(1024)
void scan_offsets(const int* __restrict__ cnt, int* __restrict__ offs) {
  __shared__ int wsum[16];
  __shared__ int carry_s;
  int lane = threadIdx.x & 63, wid = threadIdx.x >> 6;
  if (threadIdx.x == 0) carry_s = 0;
  __syncthreads();
  for (int base = 0; base < N_NODES; base += 1024) {
    int i = base + threadIdx.x;
    int v = (i < N_NODES) ? cnt[i] : 0;
    int x = v;
    #pragma unroll
    for (int o = 1; o < 64; o <<= 1) {
      int y = __shfl_up(x, o, 64);
      if (lane >= o) x += y;
    }
    if (lane == 63) wsum[wid] = x;
    __syncthreads();
    if (threadIdx.x == 0) {
      int run = carry_s;
      #pragma unroll
      for (int w = 0; w < 16; ++w) { int t = wsum[w]; wsum[w] = run; run += t; }
      carry_s = run;
    }
    __syncthreads();
    if (i < N_NODES) offs[i] = wsum[wid] + x - v;   // exclusive prefix
    __syncthreads();
  }
  if (threadIdx.x == 0) offs[N_NODES] = carry_s;
}

__global__ void scatter_edges(const void* __restrict__ ei, const int* __restrict__ offs,
                              int* __restrict__ tmp, int* __restrict__ ssrc,
                              const int* __restrict__ flags) {
  int e = blockIdx.x * blockDim.x + threadIdx.x;
  int f = flags[1];
  if (e < N_EDGES) {
    int src = load_id_clamped(ei, e, f, N_NODES);
    int dst = load_id_clamped(ei, N_EDGES + e, f, N_NODES);
    int pos = offs[dst] + atomicAdd(&tmp[dst], 1);   // bounded: counts from same clamped data
    ssrc[pos] = src;
  }
}

// ---------------- fused QKVS GEMM (MFMA 16x16x32 bf16) ----------------
// X [n][KD] bf16; WT [128][KD] bf16; biases raw (dtype per flags); outputs [n][128] bf16.
// NOTE: So may alias X (in-place, per-row): A-fragments are loaded to registers before any store.

template<int KD>
__global__ __launch_bounds__(256)
void gemm_qkvs(const short* X,
               const short* __restrict__ WTq, const short* __restrict__ WTk,
               const short* __restrict__ WTv, const short* __restrict__ WTs,
               const void* __restrict__ bq, const void* __restrict__ bk,
               const void* __restrict__ bv, const void* __restrict__ bs,
               short* Qo, short* Ko, short* Vo, short* So,
               const int* __restrict__ flags, int n)
{
  constexpr int KT = KD / 32;
  const int f    = flags[0];
  const int wid  = threadIdx.x >> 6;
  const int lane = threadIdx.x & 63;
  const int quad = lane >> 4;
  const int mm   = lane & 15;
  const int rowbase = blockIdx.x * 64 + wid * 16;
  const int arow = rowbase + mm;

  s16x8 afrag[KT];
  if (arow < n) {
    #pragma unroll
    for (int kt = 0; kt < KT; ++kt)
      afrag[kt] = *(const s16x8*)(X + (size_t)arow * KD + kt * 32 + quad * 8);
  } else {
    #pragma unroll
    for (int kt = 0; kt < KT; ++kt)
      afrag[kt] = (s16x8){0,0,0,0,0,0,0,0};
  }

  const short* wts[4] = {WTq, WTk, WTv, WTs};
  const void* bias[4] = {bq, bk, bv, bs};
  short* outs[4] = {Qo, Ko, Vo, So};

  #pragma unroll
  for (int mat = 0; mat < 4; ++mat) {
    const short* WT = wts[mat];
    f32x4 acc[8];
    #pragma unroll
    for (int c = 0; c < 8; ++c) {
      float b = load_f(bias[mat], c * 16 + mm, f);
      f32x4 av = {b, b, b, b};
      acc[c] = av;
    }
    #pragma unroll
    for (int kt = 0; kt < KT; ++kt) {
      #pragma unroll
      for (int c = 0; c < 8; ++c) {
        s16x8 bfrag = *(const s16x8*)(WT + (size_t)(c * 16 + mm) * KD + kt * 32 + quad * 8);
        acc[c] = __builtin_amdgcn_mfma_f32_16x16x32_bf16(afrag[kt], bfrag, acc[c], 0, 0, 0);
      }
    }
    short* O = outs[mat];
    #pragma unroll
    for (int c = 0; c < 8; ++c) {
      #pragma unroll
      for (int r = 0; r < 4; ++r) {
        int row = rowbase + quad * 4 + r;
        if (row < n)
          ((__hip_bfloat16*)O)[(size_t)row * 128 + c * 16 + mm] = __float2bfloat16(acc[c][r]);
      }
    }
  }
}

// ---------------- attention (online softmax over CSR segments) ----------------
// H may alias S (in-place per dst row: this block is the only reader/writer of row dst).

__global__ __launch_bounds__(128)
void attn_kernel(const __hip_bfloat16* __restrict__ Q, const __hip_bfloat16* __restrict__ K,
                 const __hip_bfloat16* __restrict__ V, const __hip_bfloat16* S,
                 const int* __restrict__ offs, const int* __restrict__ ssrc,
                 __hip_bfloat16* H)
{
  const int dst = blockIdx.x;
  const int t = threadIdx.x;
  const float q = bf2f(Q[(size_t)dst * 128 + t]) * 0.17677669529663687f; // 1/sqrt(32)
  const int e0 = offs[dst], e1 = offs[dst + 1];
  float m = -__builtin_inff(), s = 0.f, acc = 0.f;
  for (int e = e0; e < e1; ++e) {
    int src = ssrc[e];
    float kv = bf2f(K[(size_t)src * 128 + t]);
    float vv = bf2f(V[(size_t)src * 128 + t]);
    float d = q * kv;
    #pragma unroll
    for (int o = 16; o > 0; o >>= 1) d += __shfl_xor(d, o, 32);
    float mnew = fmaxf(m, d);
    float sc = __expf(m - mnew);   // first iter: exp(-inf) = 0
    float p  = __expf(d - mnew);
    s   = s * sc + p;
    acc = acc * sc + p * vv;
    m = mnew;
  }
  float o = (s > 0.f) ? (acc / s) : 0.f;
  o += bf2f(S[(size_t)dst * 128 + t]);
  H[(size_t)dst * 128 + t] = __float2bfloat16(fmaxf(o, 0.f));
}

// ---------------- pooling + final linear ----------------

__device__ __forceinline__ int lower_bound_b(const void* b, int n, long long val, int i64) {
  int lo = 0, hi = n;
  while (lo < hi) { int mid = (lo + hi) >> 1; if (load_b(b, mid, i64) < val) lo = mid + 1; else hi = mid; }
  return lo;
}

__global__ __launch_bounds__(128)
void pool_partial(const __hip_bfloat16* __restrict__ H, const void* __restrict__ batch,
                  float* __restrict__ pooled, const int* __restrict__ flags)
{
  const int g = blockIdx.x >> 3, p = blockIdx.x & 7, t = threadIdx.x;
  const int i64 = flags[1];
  const int s = lower_bound_b(batch, N_NODES, g, i64);
  const int e = lower_bound_b(batch, N_NODES, g + 1, i64);
  const int len = e - s;
  if (len <= 0) return;
  const int chunk = (len + 7) >> 3;
  const int a = s + p * chunk;
  const int b = min(a + chunk, e);
  if (a >= b) return;
  float sum = 0.f;
  for (int i = a; i < b; ++i) sum += bf2f(H[(size_t)i * 128 + t]);
  atomicAdd(&pooled[g * 128 + t], sum);
}

__global__ __launch_bounds__(128)
void pool_final(const float* __restrict__ pooled, const void* __restrict__ batch,
                const void* __restrict__ Wl, const void* __restrict__ bl,
                void* out, const int* __restrict__ flags)
{
  const int g = blockIdx.x, t = threadIdx.x;
  __shared__ float r0[128], r1[128];
  const int i64 = flags[1], f = flags[0];
  const int s = lower_bound_b(batch, N_NODES, g, i64);
  const int e = lower_bound_b(batch, N_NODES, g + 1, i64);
  const float inv = 1.0f / (float)max(e - s, 1);
  const float pc = pooled[g * 128 + t] * inv;
  r0[t] = pc * load_f(Wl, t * 2 + 0, f);
  r1[t] = pc * load_f(Wl, t * 2 + 1, f);
  __syncthreads();
  for (int o = 64; o > 0; o >>= 1) {
    if (t < o) { r0[t] += r0[t + o]; r1[t] += r1[t + o]; }
    __syncthreads();
  }
  if (t == 0) {
    float o0 = r0[0] + load_f(bl, 0, f);
    float o1 = r1[0] + load_f(bl, 1, f);
    if (f) {
      ((float*)out)[g * 2 + 0] = o0;
      ((float*)out)[g * 2 + 1] = o1;
    } else {
      ((__hip_bfloat16*)out)[g * 2 + 0] = __float2bfloat16(o0);
      ((__hip_bfloat16*)out)[g * 2 + 1] = __float2bfloat16(o1);
    }
  }
}

// ---------------- launch ----------------

extern "C" void kernel_launch(void* const* d_in, const int* in_sizes, int n_in,
                              void* d_out, int out_size, void* d_ws, size_t ws_size,
                              hipStream_t stream) {
  uintptr_t base = (uintptr_t)d_ws;
  auto take = [&](size_t bytes) -> uintptr_t {
    uintptr_t p = base;
    base += (bytes + 255) & ~(size_t)255;
    return p;
  };

  // total ~61.6 MB
  int*   flags  = (int*)take(2 * 4);
  int*   cnt    = (int*)take((size_t)N_NODES * 4);
  int*   tmp    = (int*)take((size_t)N_NODES * 4);
  int*   offs   = (int*)take((size_t)(N_NODES + 1) * 4);
  int*   ssrc   = (int*)take((size_t)N_EDGES * 4);
  short* Xc     = (short*)take((size_t)N_NODES * IN_CH * 2);
  short* Qb     = (short*)take((size_t)N_NODES * 128 * 2);
  short* Kb     = (short*)take((size_t)N_NODES * 128 * 2);
  short* Vb     = (short*)take((size_t)N_NODES * 128 * 2);
  short* Sb     = (short*)take((size_t)N_NODES * 128 * 2);   // also H and layer-2 X (in-place)
  short* wt1q   = (short*)take((size_t)IN_CH * 128 * 2);
  short* wt1k   = (short*)take((size_t)IN_CH * 128 * 2);
  short* wt1v   = (short*)take((size_t)IN_CH * 128 * 2);
  short* wt1s   = (short*)take((size_t)IN_CH * 128 * 2);
  short* wt2q   = (short*)take((size_t)HID_CH * 128 * 2);
  short* wt2k   = (short*)take((size_t)HID_CH * 128 * 2);
  short* wt2v   = (short*)take((size_t)HID_CH * 128 * 2);
  short* wt2s   = (short*)take((size_t)HID_CH * 128 * 2);
  float* pooled = (float*)take((size_t)N_GRAPHS * 128 * 4);

  detect_dtypes<<<1, 256, 0, stream>>>((const unsigned*)d_in[0], (const unsigned*)d_in[1], flags);

  conv_x<<<(N_NODES * IN_CH + 255) / 256, 256, 0, stream>>>(
      d_in[0], (__hip_bfloat16*)Xc, N_NODES * IN_CH, flags);

  conv_wt<<<(4 * 64 * 128 + 4 * 128 * 128 + 255) / 256, 256, 0, stream>>>(
      d_in[3], d_in[5], d_in[7], d_in[9], d_in[11], d_in[13], d_in[15], d_in[17],
      (__hip_bfloat16*)wt1q, (__hip_bfloat16*)wt1k, (__hip_bfloat16*)wt1v, (__hip_bfloat16*)wt1s,
      (__hip_bfloat16*)wt2q, (__hip_bfloat16*)wt2k, (__hip_bfloat16*)wt2v, (__hip_bfloat16*)wt2s,
      flags);

  init_ws<<<(N_NODES + 255) / 256, 256, 0, stream>>>(cnt, tmp, pooled);
  count_deg<<<(N_EDGES + 255) / 256, 256, 0, stream>>>(d_in[1], cnt, flags);
  scan_offsets<<<1, 1024, 0, stream>>>(cnt, offs);
  scatter_edges<<<(N_EDGES + 255) / 256, 256, 0, stream>>>(d_in[1], offs, tmp, ssrc, flags);

  const int gemm_grid = (N_NODES + 63) / 64;

  // ---- layer 1 ----
  gemm_qkvs<IN_CH><<<gemm_grid, 256, 0, stream>>>(
      Xc, wt1q, wt1k, wt1v, wt1s,
      d_in[4], d_in[6], d_in[8], d_in[10],
      Qb, Kb, Vb, Sb, flags, N_NODES);
  attn_kernel<<<N_NODES, 128, 0, stream>>>(
      (const __hip_bfloat16*)Qb, (const __hip_bfloat16*)Kb, (const __hip_bfloat16*)Vb,
      (const __hip_bfloat16*)Sb, offs, ssrc, (__hip_bfloat16*)Sb);

  // ---- layer 2 (X = Sb, S written in place into Sb) ----
  gemm_qkvs<HID_CH><<<gemm_grid, 256, 0, stream>>>(
      Sb, wt2q, wt2k, wt2v, wt2s,
      d_in[12], d_in[14], d_in[16], d_in[18],
      Qb, Kb, Vb, Sb, flags, N_NODES);
  attn_kernel<<<N_NODES, 128, 0, stream>>>(
      (const __hip_bfloat16*)Qb, (const __hip_bfloat16*)Kb, (const __hip_bfloat16*)Vb,
      (const __hip_bfloat16*)Sb, offs, ssrc, (__hip_bfloat16*)Sb);

  // ---- pool + linear ----
  pool_partial<<<N_GRAPHS * 8, 128, 0, stream>>>(
      (const __hip_bfloat16*)Sb, d_in[2], pooled, flags);
  pool_final<<<N_GRAPHS, 128, 0, stream>>>(pooled, d_in[2], d_in[19], d_in[20], d_out, flags);
}

// Round 4
// 509.759 us; speedup vs baseline: 1.2573x; 1.2573x over previous
//
#include <hip/hip_runtime.h>
#include <hip/hip_bf16.h>
#include <cstdint>
#include <cstddef>

#define N_NODES 50000
#define N_EDGES 800000
#define IN_CH 64
#define HID_CH 128
#define N_GRAPHS 64

typedef short s16x8 __attribute__((ext_vector_type(8)));
typedef float f32x4 __attribute__((ext_vector_type(4)));

__device__ __forceinline__ float bf2f(__hip_bfloat16 v) { return __bfloat162float(v); }
__device__ __forceinline__ float bfbits2f(unsigned hs) {
  union { unsigned u; float f; } v; v.u = hs << 16; return v.f;
}
__device__ __forceinline__ short f2bfs(float f) {
  __hip_bfloat16 h = __float2bfloat16(f); return *(short*)&h;
}
__device__ __forceinline__ unsigned short f2bfu(float f) {
  __hip_bfloat16 h = __float2bfloat16(f); return *(unsigned short*)&h;
}

// flags[0]: 1 if float tensors are fp32, 0 if bf16
// flags[1]: 1 if int tensors are int64, 0 if int32
__global__ void detect_dtypes(const unsigned* __restrict__ xr,
                              const unsigned* __restrict__ eir,
                              int* __restrict__ flags) {
  __shared__ int cnt_plaus, cnt_odd_nz;
  if (threadIdx.x == 0) { cnt_plaus = 0; cnt_odd_nz = 0; }
  __syncthreads();
  int t = threadIdx.x;  // 256 threads
  {
    unsigned h = xr[t] & 0xffffu;
    unsigned e = (h >> 7) & 0xffu;
    if (e == 0u || (e >= 90u && e <= 150u)) atomicAdd(&cnt_plaus, 1);
  }
  if (eir[2 * t + 1] != 0u) atomicAdd(&cnt_odd_nz, 1);
  __syncthreads();
  if (t == 0) {
    flags[0] = (cnt_plaus < 160) ? 1 : 0;
    flags[1] = (cnt_odd_nz == 0) ? 1 : 0;
  }
}

__device__ __forceinline__ float load_f(const void* p, int i, int fp32) {
  return fp32 ? ((const float*)p)[i] : bf2f(((const __hip_bfloat16*)p)[i]);
}
__device__ __forceinline__ int load_id_clamped(const void* p, int i, int i64, int limit) {
  long long v = i64 ? ((const long long*)p)[i] : (long long)((const int*)p)[i];
  if (v < 0) v = 0;
  if (v >= limit) v = limit - 1;
  return (int)v;
}
__device__ __forceinline__ long long load_b(const void* p, int i, int i64) {
  return i64 ? ((const long long*)p)[i] : (long long)((const int*)p)[i];
}

// ---------------- weight canonicalization: W[KD][128] -> WT[128][KD] bf16 ----------------

__global__ void conv_wt(const void* s0, const void* s1, const void* s2, const void* s3,
                        const void* s4, const void* s5, const void* s6, const void* s7,
                        __hip_bfloat16* d0, __hip_bfloat16* d1, __hip_bfloat16* d2, __hip_bfloat16* d3,
                        __hip_bfloat16* d4, __hip_bfloat16* d5, __hip_bfloat16* d6, __hip_bfloat16* d7,
                        const int* __restrict__ flags) {
  const void* S[8] = {s0, s1, s2, s3, s4, s5, s6, s7};
  __hip_bfloat16* D[8] = {d0, d1, d2, d3, d4, d5, d6, d7};
  int i = blockIdx.x * blockDim.x + threadIdx.x;
  int f = flags[0];
  if (i >= 4 * 64 * 128 + 4 * 128 * 128) return;
  int m, r, KD;
  if (i < 4 * 64 * 128) { m = i >> 13; r = i & 8191; KD = 64; }
  else { int j = i - 4 * 64 * 128; m = 4 + (j >> 14); r = j & 16383; KD = 128; }
  int k = r >> 7, c = r & 127;
  D[m][c * KD + k] = __float2bfloat16(load_f(S[m], r, f));
}

// ---------------- CSR build ----------------

__global__ void init_ws(int* cnt, int* tmp, float* pooled) {
  int i = blockIdx.x * blockDim.x + threadIdx.x;
  if (i < N_NODES) { cnt[i] = 0; tmp[i] = 0; }
  if (i < N_GRAPHS * HID_CH) pooled[i] = 0.f;
}

__global__ void count_deg(const void* __restrict__ ei, int* __restrict__ cnt,
                          const int* __restrict__ flags) {
  int e = blockIdx.x * blockDim.x + threadIdx.x;
  int f = flags[1];
  if (e < N_EDGES) atomicAdd(&cnt[load_id_clamped(ei, N_EDGES + e, f, N_NODES)], 1);
}

// 3-phase parallel exclusive scan over cnt[N_NODES] -> offs
#define NB_SCAN ((N_NODES + 255) / 256)   // 196

__global__ __launch_bounds__(256)
void scan1(const int* __restrict__ cnt, int* __restrict__ offs, int* __restrict__ bsum) {
  __shared__ int wsum[4];
  int t = threadIdx.x, lane = t & 63, w = t >> 6;
  int i = blockIdx.x * 256 + t;
  int v = (i < N_NODES) ? cnt[i] : 0;
  int x = v;
  #pragma unroll
  for (int o = 1; o < 64; o <<= 1) { int y = __shfl_up(x, o, 64); if (lane >= o) x += y; }
  if (lane == 63) wsum[w] = x;
  __syncthreads();
  if (t == 0) {
    int run = 0;
    #pragma unroll
    for (int k = 0; k < 4; ++k) { int tv = wsum[k]; wsum[k] = run; run += tv; }
    bsum[blockIdx.x] = run;
  }
  __syncthreads();
  if (i < N_NODES) offs[i] = wsum[w] + x - v;
}

__global__ __launch_bounds__(256)
void scan2(int* __restrict__ bsum, int* __restrict__ offs) {
  __shared__ int wsum[4];
  int t = threadIdx.x, lane = t & 63, w = t >> 6;
  int v = (t < NB_SCAN) ? bsum[t] : 0;
  int x = v;
  #pragma unroll
  for (int o = 1; o < 64; o <<= 1) { int y = __shfl_up(x, o, 64); if (lane >= o) x += y; }
  if (lane == 63) wsum[w] = x;
  __syncthreads();
  if (t == 0) {
    int run = 0;
    #pragma unroll
    for (int k = 0; k < 4; ++k) { int tv = wsum[k]; wsum[k] = run; run += tv; }
    offs[N_NODES] = run;
  }
  __syncthreads();
  if (t < NB_SCAN) bsum[t] = wsum[w] + x - v;
}

__global__ void scan3(int* __restrict__ offs, const int* __restrict__ bsum) {
  int i = blockIdx.x * blockDim.x + threadIdx.x;
  if (i < N_NODES) offs[i] += bsum[i >> 8];
}

__global__ void scatter_edges(const void* __restrict__ ei, const int* __restrict__ offs,
                              int* __restrict__ tmp, int* __restrict__ ssrc,
                              const int* __restrict__ flags) {
  int e = blockIdx.x * blockDim.x + threadIdx.x;
  int f = flags[1];
  if (e < N_EDGES) {
    int src = load_id_clamped(ei, e, f, N_NODES);
    int dst = load_id_clamped(ei, N_EDGES + e, f, N_NODES);
    int pos = offs[dst] + atomicAdd(&tmp[dst], 1);
    ssrc[pos] = src;
  }
}

// ---------------- fused QKVS GEMM (MFMA 16x16x32 bf16) ----------------
// X raw: fp32 or bf16 per xf. WT [128][KD] bf16. Outputs [n][128] bf16.
// So may alias X (in-place per-row): A-fragments are register-resident before any store.

template<int KD>
__global__ __launch_bounds__(256)
void gemm_qkvs(const void* X,
               const short* __restrict__ WTq, const short* __restrict__ WTk,
               const short* __restrict__ WTv, const short* __restrict__ WTs,
               const void* __restrict__ bq, const void* __restrict__ bk,
               const void* __restrict__ bv, const void* __restrict__ bs,
               short* Qo, short* Ko, short* Vo, short* So,
               const int* __restrict__ flags, int xf_is_flag, int n)
{
  constexpr int KT = KD / 32;
  const int f    = flags[0];
  const int xf   = xf_is_flag ? f : 0;   // layer-2 input is always bf16
  const int wid  = threadIdx.x >> 6;
  const int lane = threadIdx.x & 63;
  const int quad = lane >> 4;
  const int mm   = lane & 15;
  const int rowbase = blockIdx.x * 64 + wid * 16;
  const int arow = rowbase + mm;

  s16x8 afrag[KT];
  if (arow < n) {
    if (xf) {
      const float* xp = (const float*)X + (size_t)arow * KD;
      #pragma unroll
      for (int kt = 0; kt < KT; ++kt) {
        const float4* p = (const float4*)(xp + kt * 32 + quad * 8);
        float4 a = p[0], b = p[1];
        s16x8 fr;
        fr[0] = f2bfs(a.x); fr[1] = f2bfs(a.y); fr[2] = f2bfs(a.z); fr[3] = f2bfs(a.w);
        fr[4] = f2bfs(b.x); fr[5] = f2bfs(b.y); fr[6] = f2bfs(b.z); fr[7] = f2bfs(b.w);
        afrag[kt] = fr;
      }
    } else {
      const short* xp = (const short*)X + (size_t)arow * KD;
      #pragma unroll
      for (int kt = 0; kt < KT; ++kt)
        afrag[kt] = *(const s16x8*)(xp + kt * 32 + quad * 8);
    }
  } else {
    #pragma unroll
    for (int kt = 0; kt < KT; ++kt)
      afrag[kt] = (s16x8){0,0,0,0,0,0,0,0};
  }

  const short* wts[4] = {WTq, WTk, WTv, WTs};
  const void* bias[4] = {bq, bk, bv, bs};
  short* outs[4] = {Qo, Ko, Vo, So};

  #pragma unroll
  for (int mat = 0; mat < 4; ++mat) {
    const short* WT = wts[mat];
    f32x4 acc[8];
    #pragma unroll
    for (int c = 0; c < 8; ++c) {
      float b = load_f(bias[mat], c * 16 + mm, f);
      f32x4 av = {b, b, b, b};
      acc[c] = av;
    }
    #pragma unroll
    for (int kt = 0; kt < KT; ++kt) {
      #pragma unroll
      for (int c = 0; c < 8; ++c) {
        s16x8 bfrag = *(const s16x8*)(WT + (size_t)(c * 16 + mm) * KD + kt * 32 + quad * 8);
        acc[c] = __builtin_amdgcn_mfma_f32_16x16x32_bf16(afrag[kt], bfrag, acc[c], 0, 0, 0);
      }
    }
    short* O = outs[mat];
    #pragma unroll
    for (int c = 0; c < 8; ++c) {
      #pragma unroll
      for (int r = 0; r < 4; ++r) {
        int row = rowbase + quad * 4 + r;
        if (row < n)
          ((__hip_bfloat16*)O)[(size_t)row * 128 + c * 16 + mm] = __float2bfloat16(acc[c][r]);
      }
    }
  }
}

// ---------------- attention v2: 2ch/thread, 2 edge-groups, exp2 domain ----------------
// H may alias S (in-place per dst row).

__global__ __launch_bounds__(128)
void attn_kernel(const unsigned short* __restrict__ Q, const unsigned short* __restrict__ K,
                 const unsigned short* __restrict__ V, const unsigned short* S,
                 const int* __restrict__ offs, const int* __restrict__ ssrc,
                 unsigned short* H)
{
  __shared__ float sm[2][4], ss[2][4], sa[2][128];
  const int dst  = blockIdx.x;
  const int wave = threadIdx.x >> 6;   // edge-group 0/1
  const int t    = threadIdx.x & 63;   // channel pair 2t, 2t+1; head = t>>4
  // q scaled by 1/sqrt(32) * log2(e)  (exp2 domain)
  const float qs = 0.17677669529663687f * 1.4426950408889634f;
  unsigned qw = ((const unsigned*)(Q + (size_t)dst * 128))[t];
  const float q0 = bfbits2f(qw & 0xffffu) * qs;
  const float q1 = bfbits2f(qw >> 16) * qs;
  const int e0 = offs[dst], e1 = offs[dst + 1];

  float m = -__builtin_inff(), s = 0.f, a0 = 0.f, a1 = 0.f;
  int e = e0 + wave;
  bool have = (e < e1);
  unsigned kw = 0, vw = 0;
  if (have) {
    int src = ssrc[e];
    kw = ((const unsigned*)(K + (size_t)src * 128))[t];
    vw = ((const unsigned*)(V + (size_t)src * 128))[t];
  }
  while (have) {
    unsigned kc = kw, vc = vw;
    int en = e + 2;
    bool haven = (en < e1);
    if (haven) {
      int srcn = ssrc[en];
      kw = ((const unsigned*)(K + (size_t)srcn * 128))[t];
      vw = ((const unsigned*)(V + (size_t)srcn * 128))[t];
    }
    float k0 = bfbits2f(kc & 0xffffu), k1 = bfbits2f(kc >> 16);
    float v0 = bfbits2f(vc & 0xffffu), v1 = bfbits2f(vc >> 16);
    float d = q0 * k0 + q1 * k1;
    #pragma unroll
    for (int o = 8; o > 0; o >>= 1) d += __shfl_xor(d, o, 16);
    float mnew = fmaxf(m, d);
    float sc = exp2f(m - mnew);   // first iter: exp2(-inf)=0
    float p  = exp2f(d - mnew);
    s  = s * sc + p;
    a0 = a0 * sc + p * v0;
    a1 = a1 * sc + p * v1;
    m = mnew;
    e = en; have = haven;
  }
  if ((t & 15) == 0) { sm[wave][t >> 4] = m; ss[wave][t >> 4] = s; }
  sa[wave][2 * t]     = a0;
  sa[wave][2 * t + 1] = a1;
  __syncthreads();
  if (wave == 0) {
    int h = t >> 4;
    float m0 = sm[0][h], m1 = sm[1][h], s0 = ss[0][h], s1 = ss[1][h];
    float mstar = fmaxf(m0, m1);
    float c0 = (s0 > 0.f) ? exp2f(m0 - mstar) : 0.f;
    float c1 = (s1 > 0.f) ? exp2f(m1 - mstar) : 0.f;
    float sden = s0 * c0 + s1 * c1;
    float inv = (sden > 0.f) ? 1.0f / sden : 0.f;
    float o0 = (sa[0][2 * t]     * c0 + sa[1][2 * t]     * c1) * inv;
    float o1 = (sa[0][2 * t + 1] * c0 + sa[1][2 * t + 1] * c1) * inv;
    unsigned sw = ((const unsigned*)(S + (size_t)dst * 128))[t];
    o0 = fmaxf(o0 + bfbits2f(sw & 0xffffu), 0.f);
    o1 = fmaxf(o1 + bfbits2f(sw >> 16), 0.f);
    unsigned packed = (unsigned)f2bfu(o0) | ((unsigned)f2bfu(o1) << 16);
    ((unsigned*)(H + (size_t)dst * 128))[t] = packed;
  }
}

// ---------------- pooling + final linear ----------------

__device__ __forceinline__ int lower_bound_b(const void* b, int n, long long val, int i64) {
  int lo = 0, hi = n;
  while (lo < hi) { int mid = (lo + hi) >> 1; if (load_b(b, mid, i64) < val) lo = mid + 1; else hi = mid; }
  return lo;
}

__global__ __launch_bounds__(128)
void pool_partial(const __hip_bfloat16* __restrict__ H, const void* __restrict__ batch,
                  float* __restrict__ pooled, const int* __restrict__ flags)
{
  const int g = blockIdx.x >> 4, p = blockIdx.x & 15, t = threadIdx.x;
  const int i64 = flags[1];
  const int s = lower_bound_b(batch, N_NODES, g, i64);
  const int e = lower_bound_b(batch, N_NODES, g + 1, i64);
  const int len = e - s;
  if (len <= 0) return;
  const int chunk = (len + 15) >> 4;
  const int a = s + p * chunk;
  const int b = min(a + chunk, e);
  if (a >= b) return;
  float sum = 0.f;
  for (int i = a; i < b; ++i) sum += bf2f(H[(size_t)i * 128 + t]);
  atomicAdd(&pooled[g * 128 + t], sum);
}

__global__ __launch_bounds__(128)
void pool_final(const float* __restrict__ pooled, const void* __restrict__ batch,
                const void* __restrict__ Wl, const void* __restrict__ bl,
                void* out, const int* __restrict__ flags)
{
  const int g = blockIdx.x, t = threadIdx.x;
  __shared__ float r0[128], r1[128];
  const int i64 = flags[1], f = flags[0];
  const int s = lower_bound_b(batch, N_NODES, g, i64);
  const int e = lower_bound_b(batch, N_NODES, g + 1, i64);
  const float inv = 1.0f / (float)max(e - s, 1);
  const float pc = pooled[g * 128 + t] * inv;
  r0[t] = pc * load_f(Wl, t * 2 + 0, f);
  r1[t] = pc * load_f(Wl, t * 2 + 1, f);
  __syncthreads();
  for (int o = 64; o > 0; o >>= 1) {
    if (t < o) { r0[t] += r0[t + o]; r1[t] += r1[t + o]; }
    __syncthreads();
  }
  if (t == 0) {
    float o0 = r0[0] + load_f(bl, 0, f);
    float o1 = r1[0] + load_f(bl, 1, f);
    if (f) {
      ((float*)out)[g * 2 + 0] = o0;
      ((float*)out)[g * 2 + 1] = o1;
    } else {
      ((__hip_bfloat16*)out)[g * 2 + 0] = __float2bfloat16(o0);
      ((__hip_bfloat16*)out)[g * 2 + 1] = __float2bfloat16(o1);
    }
  }
}

// ---------------- launch ----------------

extern "C" void kernel_launch(void* const* d_in, const int* in_sizes, int n_in,
                              void* d_out, int out_size, void* d_ws, size_t ws_size,
                              hipStream_t stream) {
  uintptr_t base = (uintptr_t)d_ws;
  auto take = [&](size_t bytes) -> uintptr_t {
    uintptr_t p = base;
    base += (bytes + 255) & ~(size_t)255;
    return p;
  };

  int*   flags  = (int*)take(2 * 4);
  int*   cnt    = (int*)take((size_t)N_NODES * 4);
  int*   tmp    = (int*)take((size_t)N_NODES * 4);
  int*   offs   = (int*)take((size_t)(N_NODES + 1) * 4);
  int*   bsum   = (int*)take((size_t)NB_SCAN * 4);
  int*   ssrc   = (int*)take((size_t)N_EDGES * 4);
  short* Qb     = (short*)take((size_t)N_NODES * 128 * 2);
  short* Kb     = (short*)take((size_t)N_NODES * 128 * 2);
  short* Vb     = (short*)take((size_t)N_NODES * 128 * 2);
  short* Sb     = (short*)take((size_t)N_NODES * 128 * 2);   // also H and layer-2 X (in-place)
  short* wt1q   = (short*)take((size_t)IN_CH * 128 * 2);
  short* wt1k   = (short*)take((size_t)IN_CH * 128 * 2);
  short* wt1v   = (short*)take((size_t)IN_CH * 128 * 2);
  short* wt1s   = (short*)take((size_t)IN_CH * 128 * 2);
  short* wt2q   = (short*)take((size_t)HID_CH * 128 * 2);
  short* wt2k   = (short*)take((size_t)HID_CH * 128 * 2);
  short* wt2v   = (short*)take((size_t)HID_CH * 128 * 2);
  short* wt2s   = (short*)take((size_t)HID_CH * 128 * 2);
  float* pooled = (float*)take((size_t)N_GRAPHS * 128 * 4);

  detect_dtypes<<<1, 256, 0, stream>>>((const unsigned*)d_in[0], (const unsigned*)d_in[1], flags);

  conv_wt<<<(4 * 64 * 128 + 4 * 128 * 128 + 255) / 256, 256, 0, stream>>>(
      d_in[3], d_in[5], d_in[7], d_in[9], d_in[11], d_in[13], d_in[15], d_in[17],
      (__hip_bfloat16*)wt1q, (__hip_bfloat16*)wt1k, (__hip_bfloat16*)wt1v, (__hip_bfloat16*)wt1s,
      (__hip_bfloat16*)wt2q, (__hip_bfloat16*)wt2k, (__hip_bfloat16*)wt2v, (__hip_bfloat16*)wt2s,
      flags);

  init_ws<<<(N_NODES + 255) / 256, 256, 0, stream>>>(cnt, tmp, pooled);
  count_deg<<<(N_EDGES + 255) / 256, 256, 0, stream>>>(d_in[1], cnt, flags);
  scan1<<<NB_SCAN, 256, 0, stream>>>(cnt, offs, bsum);
  scan2<<<1, 256, 0, stream>>>(bsum, offs);
  scan3<<<NB_SCAN, 256, 0, stream>>>(offs, bsum);
  scatter_edges<<<(N_EDGES + 255) / 256, 256, 0, stream>>>(d_in[1], offs, tmp, ssrc, flags);

  const int gemm_grid = (N_NODES + 63) / 64;

  // ---- layer 1 (raw x input, dtype per flags) ----
  gemm_qkvs<IN_CH><<<gemm_grid, 256, 0, stream>>>(
      d_in[0], wt1q, wt1k, wt1v, wt1s,
      d_in[4], d_in[6], d_in[8], d_in[10],
      Qb, Kb, Vb, Sb, flags, 1, N_NODES);
  attn_kernel<<<N_NODES, 128, 0, stream>>>(
      (const unsigned short*)Qb, (const unsigned short*)Kb, (const unsigned short*)Vb,
      (const unsigned short*)Sb, offs, ssrc, (unsigned short*)Sb);

  // ---- layer 2 (X = Sb bf16, S written in place into Sb) ----
  gemm_qkvs<HID_CH><<<gemm_grid, 256, 0, stream>>>(
      Sb, wt2q, wt2k, wt2v, wt2s,
      d_in[12], d_in[14], d_in[16], d_in[18],
      Qb, Kb, Vb, Sb, flags, 0, N_NODES);
  attn_kernel<<<N_NODES, 128, 0, stream>>>(
      (const unsigned short*)Qb, (const unsigned short*)Kb, (const unsigned short*)Vb,
      (const unsigned short*)Sb, offs, ssrc, (unsigned short*)Sb);

  // ---- pool + linear ----
  pool_partial<<<N_GRAPHS * 16, 128, 0, stream>>>(
      (const __hip_bfloat16*)Sb, d_in[2], pooled, flags);
  pool_final<<<N_GRAPHS, 128, 0, stream>>>(pooled, d_in[2], d_in[19], d_in[20], d_out, flags);
}

// Round 5
// 438.597 us; speedup vs baseline: 1.4612x; 1.1622x over previous
//
#include <hip/hip_runtime.h>
#include <hip/hip_bf16.h>
#include <cstdint>
#include <cstddef>

#define N_NODES 50000
#define N_EDGES 800000
#define IN_CH 64
#define HID_CH 128
#define N_GRAPHS 64

typedef short s16x8 __attribute__((ext_vector_type(8)));
typedef float f32x4 __attribute__((ext_vector_type(4)));

__device__ __forceinline__ float bf2f(__hip_bfloat16 v) { return __bfloat162float(v); }
__device__ __forceinline__ float bfbits2f(unsigned hs) {
  union { unsigned u; float f; } v; v.u = hs << 16; return v.f;
}
__device__ __forceinline__ float bfhi2f(unsigned w) {
  union { unsigned u; float f; } v; v.u = w & 0xffff0000u; return v.f;
}
__device__ __forceinline__ short f2bfs(float f) {
  __hip_bfloat16 h = __float2bfloat16(f); return *(short*)&h;
}
__device__ __forceinline__ unsigned short f2bfu(float f) {
  __hip_bfloat16 h = __float2bfloat16(f); return *(unsigned short*)&h;
}

// flags[0]: 1 if float tensors are fp32, 0 if bf16
// flags[1]: 1 if int tensors are int64, 0 if int32
__global__ void detect_dtypes(const unsigned* __restrict__ xr,
                              const unsigned* __restrict__ eir,
                              int* __restrict__ flags) {
  __shared__ int cnt_plaus, cnt_odd_nz;
  if (threadIdx.x == 0) { cnt_plaus = 0; cnt_odd_nz = 0; }
  __syncthreads();
  int t = threadIdx.x;  // 256 threads
  {
    unsigned h = xr[t] & 0xffffu;
    unsigned e = (h >> 7) & 0xffu;
    if (e == 0u || (e >= 90u && e <= 150u)) atomicAdd(&cnt_plaus, 1);
  }
  if (eir[2 * t + 1] != 0u) atomicAdd(&cnt_odd_nz, 1);
  __syncthreads();
  if (t == 0) {
    flags[0] = (cnt_plaus < 160) ? 1 : 0;
    flags[1] = (cnt_odd_nz == 0) ? 1 : 0;
  }
}

__device__ __forceinline__ float load_f(const void* p, int i, int fp32) {
  return fp32 ? ((const float*)p)[i] : bf2f(((const __hip_bfloat16*)p)[i]);
}
__device__ __forceinline__ int load_id_clamped(const void* p, int i, int i64, int limit) {
  long long v = i64 ? ((const long long*)p)[i] : (long long)((const int*)p)[i];
  if (v < 0) v = 0;
  if (v >= limit) v = limit - 1;
  return (int)v;
}
__device__ __forceinline__ long long load_b(const void* p, int i, int i64) {
  return i64 ? ((const long long*)p)[i] : (long long)((const int*)p)[i];
}

// ---------------- weight canonicalization: W[KD][128] -> WT[128][KD] bf16 ----------------

__global__ void conv_wt(const void* s0, const void* s1, const void* s2, const void* s3,
                        const void* s4, const void* s5, const void* s6, const void* s7,
                        __hip_bfloat16* d0, __hip_bfloat16* d1, __hip_bfloat16* d2, __hip_bfloat16* d3,
                        __hip_bfloat16* d4, __hip_bfloat16* d5, __hip_bfloat16* d6, __hip_bfloat16* d7,
                        const int* __restrict__ flags) {
  const void* S[8] = {s0, s1, s2, s3, s4, s5, s6, s7};
  __hip_bfloat16* D[8] = {d0, d1, d2, d3, d4, d5, d6, d7};
  int i = blockIdx.x * blockDim.x + threadIdx.x;
  int f = flags[0];
  if (i >= 4 * 64 * 128 + 4 * 128 * 128) return;
  int m, r, KD;
  if (i < 4 * 64 * 128) { m = i >> 13; r = i & 8191; KD = 64; }
  else { int j = i - 4 * 64 * 128; m = 4 + (j >> 14); r = j & 16383; KD = 128; }
  int k = r >> 7, c = r & 127;
  D[m][c * KD + k] = __float2bfloat16(load_f(S[m], r, f));
}

// ---------------- CSR build ----------------

__global__ void init_ws(int* cnt, int* tmp, float* pooled) {
  int i = blockIdx.x * blockDim.x + threadIdx.x;
  if (i < N_NODES) { cnt[i] = 0; tmp[i] = 0; }
  if (i < N_GRAPHS * HID_CH) pooled[i] = 0.f;
}

__global__ void count_deg(const void* __restrict__ ei, int* __restrict__ cnt,
                          const int* __restrict__ flags) {
  int e = blockIdx.x * blockDim.x + threadIdx.x;
  int f = flags[1];
  if (e < N_EDGES) atomicAdd(&cnt[load_id_clamped(ei, N_EDGES + e, f, N_NODES)], 1);
}

// 3-phase parallel exclusive scan over cnt[N_NODES] -> offs
#define NB_SCAN ((N_NODES + 255) / 256)   // 196

__global__ __launch_bounds__(256)
void scan1(const int* __restrict__ cnt, int* __restrict__ offs, int* __restrict__ bsum) {
  __shared__ int wsum[4];
  int t = threadIdx.x, lane = t & 63, w = t >> 6;
  int i = blockIdx.x * 256 + t;
  int v = (i < N_NODES) ? cnt[i] : 0;
  int x = v;
  #pragma unroll
  for (int o = 1; o < 64; o <<= 1) { int y = __shfl_up(x, o, 64); if (lane >= o) x += y; }
  if (lane == 63) wsum[w] = x;
  __syncthreads();
  if (t == 0) {
    int run = 0;
    #pragma unroll
    for (int k = 0; k < 4; ++k) { int tv = wsum[k]; wsum[k] = run; run += tv; }
    bsum[blockIdx.x] = run;
  }
  __syncthreads();
  if (i < N_NODES) offs[i] = wsum[w] + x - v;
}

__global__ __launch_bounds__(256)
void scan2(int* __restrict__ bsum, int* __restrict__ offs) {
  __shared__ int wsum[4];
  int t = threadIdx.x, lane = t & 63, w = t >> 6;
  int v = (t < NB_SCAN) ? bsum[t] : 0;
  int x = v;
  #pragma unroll
  for (int o = 1; o < 64; o <<= 1) { int y = __shfl_up(x, o, 64); if (lane >= o) x += y; }
  if (lane == 63) wsum[w] = x;
  __syncthreads();
  if (t == 0) {
    int run = 0;
    #pragma unroll
    for (int k = 0; k < 4; ++k) { int tv = wsum[k]; wsum[k] = run; run += tv; }
    offs[N_NODES] = run;
  }
  __syncthreads();
  if (t < NB_SCAN) bsum[t] = wsum[w] + x - v;
}

__global__ void scan3(int* __restrict__ offs, const int* __restrict__ bsum) {
  int i = blockIdx.x * blockDim.x + threadIdx.x;
  if (i < N_NODES) offs[i] += bsum[i >> 8];
}

__global__ void scatter_edges(const void* __restrict__ ei, const int* __restrict__ offs,
                              int* __restrict__ tmp, int* __restrict__ ssrc,
                              const int* __restrict__ flags) {
  int e = blockIdx.x * blockDim.x + threadIdx.x;
  int f = flags[1];
  if (e < N_EDGES) {
    int src = load_id_clamped(ei, e, f, N_NODES);
    int dst = load_id_clamped(ei, N_EDGES + e, f, N_NODES);
    int pos = offs[dst] + atomicAdd(&tmp[dst], 1);
    ssrc[pos] = src;
  }
}

// ---------------- fused QKVS GEMM (MFMA 16x16x32 bf16) ----------------
// X raw: fp32 or bf16 per xf. WT [128][KD] bf16. Outputs [n][128] bf16.
// So may alias X (in-place per-row): A-fragments are register-resident before any store.

template<int KD>
__global__ __launch_bounds__(256)
void gemm_qkvs(const void* X,
               const short* __restrict__ WTq, const short* __restrict__ WTk,
               const short* __restrict__ WTv, const short* __restrict__ WTs,
               const void* __restrict__ bq, const void* __restrict__ bk,
               const void* __restrict__ bv, const void* __restrict__ bs,
               short* Qo, short* Ko, short* Vo, short* So,
               const int* __restrict__ flags, int xf_is_flag, int n)
{
  constexpr int KT = KD / 32;
  const int f    = flags[0];
  const int xf   = xf_is_flag ? f : 0;   // layer-2 input is always bf16
  const int wid  = threadIdx.x >> 6;
  const int lane = threadIdx.x & 63;
  const int quad = lane >> 4;
  const int mm   = lane & 15;
  const int rowbase = blockIdx.x * 64 + wid * 16;
  const int arow = rowbase + mm;

  s16x8 afrag[KT];
  if (arow < n) {
    if (xf) {
      const float* xp = (const float*)X + (size_t)arow * KD;
      #pragma unroll
      for (int kt = 0; kt < KT; ++kt) {
        const float4* p = (const float4*)(xp + kt * 32 + quad * 8);
        float4 a = p[0], b = p[1];
        s16x8 fr;
        fr[0] = f2bfs(a.x); fr[1] = f2bfs(a.y); fr[2] = f2bfs(a.z); fr[3] = f2bfs(a.w);
        fr[4] = f2bfs(b.x); fr[5] = f2bfs(b.y); fr[6] = f2bfs(b.z); fr[7] = f2bfs(b.w);
        afrag[kt] = fr;
      }
    } else {
      const short* xp = (const short*)X + (size_t)arow * KD;
      #pragma unroll
      for (int kt = 0; kt < KT; ++kt)
        afrag[kt] = *(const s16x8*)(xp + kt * 32 + quad * 8);
    }
  } else {
    #pragma unroll
    for (int kt = 0; kt < KT; ++kt)
      afrag[kt] = (s16x8){0,0,0,0,0,0,0,0};
  }

  const short* wts[4] = {WTq, WTk, WTv, WTs};
  const void* bias[4] = {bq, bk, bv, bs};
  short* outs[4] = {Qo, Ko, Vo, So};

  #pragma unroll
  for (int mat = 0; mat < 4; ++mat) {
    const short* WT = wts[mat];
    f32x4 acc[8];
    #pragma unroll
    for (int c = 0; c < 8; ++c) {
      float b = load_f(bias[mat], c * 16 + mm, f);
      f32x4 av = {b, b, b, b};
      acc[c] = av;
    }
    #pragma unroll
    for (int kt = 0; kt < KT; ++kt) {
      #pragma unroll
      for (int c = 0; c < 8; ++c) {
        s16x8 bfrag = *(const s16x8*)(WT + (size_t)(c * 16 + mm) * KD + kt * 32 + quad * 8);
        acc[c] = __builtin_amdgcn_mfma_f32_16x16x32_bf16(afrag[kt], bfrag, acc[c], 0, 0, 0);
      }
    }
    short* O = outs[mat];
    #pragma unroll
    for (int c = 0; c < 8; ++c) {
      #pragma unroll
      for (int r = 0; r < 4; ++r) {
        int row = rowbase + quad * 4 + r;
        if (row < n)
          ((__hip_bfloat16*)O)[(size_t)row * 128 + c * 16 + mm] = __float2bfloat16(acc[c][r]);
      }
    }
  }
}

// ---------------- attention v3 ----------------
// 1 wave per dst (4 dsts/block). Within a wave: 4 edge slots x 16 channel-lanes.
// Lane = (sub<<4)|cl: sub = edge slot, cl covers channels 8cl..8cl+7 (head = cl>>2).
// No-max softmax (logits are tiny: |d| <~ 2), exp2 domain, register double-buffered K/V gather.
// H may alias S (in-place per dst row).

__global__ __launch_bounds__(256)
void attn_kernel(const unsigned short* __restrict__ Q, const unsigned short* __restrict__ K,
                 const unsigned short* __restrict__ V, const unsigned short* S,
                 const int* __restrict__ offs, const int* __restrict__ ssrc,
                 unsigned short* H)
{
  const int dst = blockIdx.x * 4 + (threadIdx.x >> 6);
  if (dst >= N_NODES) return;               // wave-uniform
  const int lane = threadIdx.x & 63;
  const int sub  = lane >> 4;
  const int cl   = lane & 15;

  // 1/sqrt(32) * log2(e): exp2-domain scaling folded into q
  const float qs = 0.17677669529663687f * 1.4426950408889634f;
  uint4 qw = *(const uint4*)(Q + (size_t)dst * 128 + cl * 8);
  float q[8], a[8];
  #pragma unroll
  for (int i = 0; i < 4; ++i) {
    unsigned w = ((unsigned*)&qw)[i];
    q[2 * i]     = bfbits2f(w & 0xffffu) * qs;
    q[2 * i + 1] = bfhi2f(w) * qs;
    a[2 * i] = 0.f; a[2 * i + 1] = 0.f;
  }
  float s = 0.f;

  const int e0 = offs[dst], e1 = offs[dst + 1];
  const int iters = (e1 - e0 + 3) >> 2;

  if (iters > 0) {
    int e = e0 + sub;
    bool have = (e < e1);
    int src = have ? ssrc[e] : ssrc[e0];
    float ph = have ? 1.f : 0.f;
    uint4 kw = *(const uint4*)(K + (size_t)src * 128 + cl * 8);
    uint4 vw = *(const uint4*)(V + (size_t)src * 128 + cl * 8);

    for (int it = 0; it < iters; ++it) {
      uint4 kwn, vwn;
      int en = e + 4;
      bool haven = (en < e1);
      float phn = haven ? 1.f : 0.f;
      if (it + 1 < iters) {                 // wave-uniform branch
        int srcn = haven ? ssrc[en] : ssrc[e0];
        kwn = *(const uint4*)(K + (size_t)srcn * 128 + cl * 8);
        vwn = *(const uint4*)(V + (size_t)srcn * 128 + cl * 8);
      } else {
        kwn = kw; vwn = vw;
      }
      // dot over this lane's 8 channels
      float d = 0.f;
      #pragma unroll
      for (int i = 0; i < 4; ++i) {
        unsigned w = ((unsigned*)&kw)[i];
        d += q[2 * i]     * bfbits2f(w & 0xffffu);
        d += q[2 * i + 1] * bfhi2f(w);
      }
      // reduce over the 4 lanes of this head
      d += __shfl_xor(d, 1, 64);
      d += __shfl_xor(d, 2, 64);
      float p = exp2f(d) * ph;
      s += p;
      #pragma unroll
      for (int i = 0; i < 4; ++i) {
        unsigned w = ((unsigned*)&vw)[i];
        a[2 * i]     += p * bfbits2f(w & 0xffffu);
        a[2 * i + 1] += p * bfhi2f(w);
      }
      kw = kwn; vw = vwn; e = en; ph = phn;
    }
  }

  // merge the 4 edge slots
  s += __shfl_xor(s, 16, 64);
  s += __shfl_xor(s, 32, 64);
  #pragma unroll
  for (int i = 0; i < 8; ++i) {
    a[i] += __shfl_xor(a[i], 16, 64);
    a[i] += __shfl_xor(a[i], 32, 64);
  }
  const float inv = (s > 0.f) ? (1.0f / s) : 0.f;

  if (sub == 0) {
    uint4 sw = *(const uint4*)(S + (size_t)dst * 128 + cl * 8);
    uint4 ow;
    #pragma unroll
    for (int i = 0; i < 4; ++i) {
      unsigned w = ((unsigned*)&sw)[i];
      float o0 = fmaxf(a[2 * i] * inv     + bfbits2f(w & 0xffffu), 0.f);
      float o1 = fmaxf(a[2 * i + 1] * inv + bfhi2f(w), 0.f);
      ((unsigned*)&ow)[i] = (unsigned)f2bfu(o0) | ((unsigned)f2bfu(o1) << 16);
    }
    *(uint4*)(H + (size_t)dst * 128 + cl * 8) = ow;
  }
}

// ---------------- pooling + final linear ----------------

__device__ __forceinline__ int lower_bound_b(const void* b, int n, long long val, int i64) {
  int lo = 0, hi = n;
  while (lo < hi) { int mid = (lo + hi) >> 1; if (load_b(b, mid, i64) < val) lo = mid + 1; else hi = mid; }
  return lo;
}

__global__ __launch_bounds__(128)
void pool_partial(const __hip_bfloat16* __restrict__ H, const void* __restrict__ batch,
                  float* __restrict__ pooled, const int* __restrict__ flags)
{
  const int g = blockIdx.x >> 4, p = blockIdx.x & 15, t = threadIdx.x;
  const int i64 = flags[1];
  const int s = lower_bound_b(batch, N_NODES, g, i64);
  const int e = lower_bound_b(batch, N_NODES, g + 1, i64);
  const int len = e - s;
  if (len <= 0) return;
  const int chunk = (len + 15) >> 4;
  const int a = s + p * chunk;
  const int b = min(a + chunk, e);
  if (a >= b) return;
  float sum = 0.f;
  for (int i = a; i < b; ++i) sum += bf2f(H[(size_t)i * 128 + t]);
  atomicAdd(&pooled[g * 128 + t], sum);
}

__global__ __launch_bounds__(128)
void pool_final(const float* __restrict__ pooled, const void* __restrict__ batch,
                const void* __restrict__ Wl, const void* __restrict__ bl,
                void* out, const int* __restrict__ flags)
{
  const int g = blockIdx.x, t = threadIdx.x;
  __shared__ float r0[128], r1[128];
  const int i64 = flags[1], f = flags[0];
  const int s = lower_bound_b(batch, N_NODES, g, i64);
  const int e = lower_bound_b(batch, N_NODES, g + 1, i64);
  const float inv = 1.0f / (float)max(e - s, 1);
  const float pc = pooled[g * 128 + t] * inv;
  r0[t] = pc * load_f(Wl, t * 2 + 0, f);
  r1[t] = pc * load_f(Wl, t * 2 + 1, f);
  __syncthreads();
  for (int o = 64; o > 0; o >>= 1) {
    if (t < o) { r0[t] += r0[t + o]; r1[t] += r1[t + o]; }
    __syncthreads();
  }
  if (t == 0) {
    float o0 = r0[0] + load_f(bl, 0, f);
    float o1 = r1[0] + load_f(bl, 1, f);
    if (f) {
      ((float*)out)[g * 2 + 0] = o0;
      ((float*)out)[g * 2 + 1] = o1;
    } else {
      ((__hip_bfloat16*)out)[g * 2 + 0] = __float2bfloat16(o0);
      ((__hip_bfloat16*)out)[g * 2 + 1] = __float2bfloat16(o1);
    }
  }
}

// ---------------- launch ----------------

extern "C" void kernel_launch(void* const* d_in, const int* in_sizes, int n_in,
                              void* d_out, int out_size, void* d_ws, size_t ws_size,
                              hipStream_t stream) {
  uintptr_t base = (uintptr_t)d_ws;
  auto take = [&](size_t bytes) -> uintptr_t {
    uintptr_t p = base;
    base += (bytes + 255) & ~(size_t)255;
    return p;
  };

  int*   flags  = (int*)take(2 * 4);
  int*   cnt    = (int*)take((size_t)N_NODES * 4);
  int*   tmp    = (int*)take((size_t)N_NODES * 4);
  int*   offs   = (int*)take((size_t)(N_NODES + 1) * 4);
  int*   bsum   = (int*)take((size_t)NB_SCAN * 4);
  int*   ssrc   = (int*)take((size_t)N_EDGES * 4);
  short* Qb     = (short*)take((size_t)N_NODES * 128 * 2);
  short* Kb     = (short*)take((size_t)N_NODES * 128 * 2);
  short* Vb     = (short*)take((size_t)N_NODES * 128 * 2);
  short* Sb     = (short*)take((size_t)N_NODES * 128 * 2);   // also H and layer-2 X (in-place)
  short* wt1q   = (short*)take((size_t)IN_CH * 128 * 2);
  short* wt1k   = (short*)take((size_t)IN_CH * 128 * 2);
  short* wt1v   = (short*)take((size_t)IN_CH * 128 * 2);
  short* wt1s   = (short*)take((size_t)IN_CH * 128 * 2);
  short* wt2q   = (short*)take((size_t)HID_CH * 128 * 2);
  short* wt2k   = (short*)take((size_t)HID_CH * 128 * 2);
  short* wt2v   = (short*)take((size_t)HID_CH * 128 * 2);
  short* wt2s   = (short*)take((size_t)HID_CH * 128 * 2);
  float* pooled = (float*)take((size_t)N_GRAPHS * 128 * 4);

  detect_dtypes<<<1, 256, 0, stream>>>((const unsigned*)d_in[0], (const unsigned*)d_in[1], flags);

  conv_wt<<<(4 * 64 * 128 + 4 * 128 * 128 + 255) / 256, 256, 0, stream>>>(
      d_in[3], d_in[5], d_in[7], d_in[9], d_in[11], d_in[13], d_in[15], d_in[17],
      (__hip_bfloat16*)wt1q, (__hip_bfloat16*)wt1k, (__hip_bfloat16*)wt1v, (__hip_bfloat16*)wt1s,
      (__hip_bfloat16*)wt2q, (__hip_bfloat16*)wt2k, (__hip_bfloat16*)wt2v, (__hip_bfloat16*)wt2s,
      flags);

  init_ws<<<(N_NODES + 255) / 256, 256, 0, stream>>>(cnt, tmp, pooled);
  count_deg<<<(N_EDGES + 255) / 256, 256, 0, stream>>>(d_in[1], cnt, flags);
  scan1<<<NB_SCAN, 256, 0, stream>>>(cnt, offs, bsum);
  scan2<<<1, 256, 0, stream>>>(bsum, offs);
  scan3<<<NB_SCAN, 256, 0, stream>>>(offs, bsum);
  scatter_edges<<<(N_EDGES + 255) / 256, 256, 0, stream>>>(d_in[1], offs, tmp, ssrc, flags);

  const int gemm_grid = (N_NODES + 63) / 64;
  const int attn_grid = (N_NODES + 3) / 4;

  // ---- layer 1 (raw x input, dtype per flags) ----
  gemm_qkvs<IN_CH><<<gemm_grid, 256, 0, stream>>>(
      d_in[0], wt1q, wt1k, wt1v, wt1s,
      d_in[4], d_in[6], d_in[8], d_in[10],
      Qb, Kb, Vb, Sb, flags, 1, N_NODES);
  attn_kernel<<<attn_grid, 256, 0, stream>>>(
      (const unsigned short*)Qb, (const unsigned short*)Kb, (const unsigned short*)Vb,
      (const unsigned short*)Sb, offs, ssrc, (unsigned short*)Sb);

  // ---- layer 2 (X = Sb bf16, S written in place into Sb) ----
  gemm_qkvs<HID_CH><<<gemm_grid, 256, 0, stream>>>(
      Sb, wt2q, wt2k, wt2v, wt2s,
      d_in[12], d_in[14], d_in[16], d_in[18],
      Qb, Kb, Vb, Sb, flags, 0, N_NODES);
  attn_kernel<<<attn_grid, 256, 0, stream>>>(
      (const unsigned short*)Qb, (const unsigned short*)Kb, (const unsigned short*)Vb,
      (const unsigned short*)Sb, offs, ssrc, (unsigned short*)Sb);

  // ---- pool + linear ----
  pool_partial<<<N_GRAPHS * 16, 128, 0, stream>>>(
      (const __hip_bfloat16*)Sb, d_in[2], pooled, flags);
  pool_final<<<N_GRAPHS, 128, 0, stream>>>(pooled, d_in[2], d_in[19], d_in[20], d_out, flags);
}

// Round 6
// 376.915 us; speedup vs baseline: 1.7004x; 1.1637x over previous
//
#include <hip/hip_runtime.h>
#include <hip/hip_bf16.h>
#include <cstdint>
#include <cstddef>

#define N_NODES 50000
#define N_EDGES 800000
#define IN_CH 64
#define HID_CH 128
#define N_GRAPHS 64

typedef short s16x8 __attribute__((ext_vector_type(8)));
typedef float f32x4 __attribute__((ext_vector_type(4)));

__device__ __forceinline__ float bf2f(__hip_bfloat16 v) { return __bfloat162float(v); }
__device__ __forceinline__ float bfbits2f(unsigned hs) {
  union { unsigned u; float f; } v; v.u = hs << 16; return v.f;
}
__device__ __forceinline__ float bfhi2f(unsigned w) {
  union { unsigned u; float f; } v; v.u = w & 0xffff0000u; return v.f;
}
__device__ __forceinline__ short f2bfs(float f) {
  __hip_bfloat16 h = __float2bfloat16(f); return *(short*)&h;
}
__device__ __forceinline__ unsigned short f2bfu(float f) {
  __hip_bfloat16 h = __float2bfloat16(f); return *(unsigned short*)&h;
}

// flags[0]: 1 if float tensors are fp32, 0 if bf16
// flags[1]: 1 if int tensors are int64, 0 if int32
__global__ void detect_dtypes(const unsigned* __restrict__ xr,
                              const unsigned* __restrict__ eir,
                              int* __restrict__ flags) {
  __shared__ int cnt_plaus, cnt_odd_nz;
  if (threadIdx.x == 0) { cnt_plaus = 0; cnt_odd_nz = 0; }
  __syncthreads();
  int t = threadIdx.x;  // 256 threads
  {
    unsigned h = xr[t] & 0xffffu;
    unsigned e = (h >> 7) & 0xffu;
    if (e == 0u || (e >= 90u && e <= 150u)) atomicAdd(&cnt_plaus, 1);
  }
  if (eir[2 * t + 1] != 0u) atomicAdd(&cnt_odd_nz, 1);
  __syncthreads();
  if (t == 0) {
    flags[0] = (cnt_plaus < 160) ? 1 : 0;
    flags[1] = (cnt_odd_nz == 0) ? 1 : 0;
  }
}

__device__ __forceinline__ float load_f(const void* p, int i, int fp32) {
  return fp32 ? ((const float*)p)[i] : bf2f(((const __hip_bfloat16*)p)[i]);
}
__device__ __forceinline__ int load_id_clamped(const void* p, int i, int i64, int limit) {
  long long v = i64 ? ((const long long*)p)[i] : (long long)((const int*)p)[i];
  if (v < 0) v = 0;
  if (v >= limit) v = limit - 1;
  return (int)v;
}
__device__ __forceinline__ long long load_b(const void* p, int i, int i64) {
  return i64 ? ((const long long*)p)[i] : (long long)((const int*)p)[i];
}

// ---------------- weight canonicalization ----------------
// W logical [KD][128] (element (k,c) at k*128+c) -> LDS-image layout:
// WT[((k>>3)*128 + c)*8 + (k&7)]  i.e. [k-chunk][col][8 shorts]
// This makes GEMM staging a pure linear copy and B-fragment ds_reads
// lane-consecutive 16B (conflict-free).

__global__ void conv_wt(const void* s0, const void* s1, const void* s2, const void* s3,
                        const void* s4, const void* s5, const void* s6, const void* s7,
                        __hip_bfloat16* d0, __hip_bfloat16* d1, __hip_bfloat16* d2, __hip_bfloat16* d3,
                        __hip_bfloat16* d4, __hip_bfloat16* d5, __hip_bfloat16* d6, __hip_bfloat16* d7,
                        const int* __restrict__ flags) {
  const void* S[8] = {s0, s1, s2, s3, s4, s5, s6, s7};
  __hip_bfloat16* D[8] = {d0, d1, d2, d3, d4, d5, d6, d7};
  int i = blockIdx.x * blockDim.x + threadIdx.x;
  int f = flags[0];
  if (i >= 4 * 64 * 128 + 4 * 128 * 128) return;
  int m, r;
  if (i < 4 * 64 * 128) { m = i >> 13; r = i & 8191; }
  else { int j = i - 4 * 64 * 128; m = 4 + (j >> 14); r = j & 16383; }
  int k = r >> 7, c = r & 127;
  D[m][(((k >> 3) * 128 + c) << 3) + (k & 7)] = __float2bfloat16(load_f(S[m], r, f));
}

// ---------------- CSR build ----------------

__global__ void init_ws(int* cnt, int* tmp, float* pooled) {
  int i = blockIdx.x * blockDim.x + threadIdx.x;
  if (i < N_NODES) { cnt[i] = 0; tmp[i] = 0; }
  if (i < N_GRAPHS * HID_CH) pooled[i] = 0.f;
}

__global__ void count_deg(const void* __restrict__ ei, int* __restrict__ cnt,
                          const int* __restrict__ flags) {
  int e = blockIdx.x * blockDim.x + threadIdx.x;
  int f = flags[1];
  if (e < N_EDGES) atomicAdd(&cnt[load_id_clamped(ei, N_EDGES + e, f, N_NODES)], 1);
}

// 3-phase parallel exclusive scan over cnt[N_NODES] -> offs
#define NB_SCAN ((N_NODES + 255) / 256)   // 196

__global__ __launch_bounds__(256)
void scan1(const int* __restrict__ cnt, int* __restrict__ offs, int* __restrict__ bsum) {
  __shared__ int wsum[4];
  int t = threadIdx.x, lane = t & 63, w = t >> 6;
  int i = blockIdx.x * 256 + t;
  int v = (i < N_NODES) ? cnt[i] : 0;
  int x = v;
  #pragma unroll
  for (int o = 1; o < 64; o <<= 1) { int y = __shfl_up(x, o, 64); if (lane >= o) x += y; }
  if (lane == 63) wsum[w] = x;
  __syncthreads();
  if (t == 0) {
    int run = 0;
    #pragma unroll
    for (int k = 0; k < 4; ++k) { int tv = wsum[k]; wsum[k] = run; run += tv; }
    bsum[blockIdx.x] = run;
  }
  __syncthreads();
  if (i < N_NODES) offs[i] = wsum[w] + x - v;
}

__global__ __launch_bounds__(256)
void scan2(int* __restrict__ bsum, int* __restrict__ offs) {
  __shared__ int wsum[4];
  int t = threadIdx.x, lane = t & 63, w = t >> 6;
  int v = (t < NB_SCAN) ? bsum[t] : 0;
  int x = v;
  #pragma unroll
  for (int o = 1; o < 64; o <<= 1) { int y = __shfl_up(x, o, 64); if (lane >= o) x += y; }
  if (lane == 63) wsum[w] = x;
  __syncthreads();
  if (t == 0) {
    int run = 0;
    #pragma unroll
    for (int k = 0; k < 4; ++k) { int tv = wsum[k]; wsum[k] = run; run += tv; }
    offs[N_NODES] = run;
  }
  __syncthreads();
  if (t < NB_SCAN) bsum[t] = wsum[w] + x - v;
}

__global__ void scan3(int* __restrict__ offs, const int* __restrict__ bsum) {
  int i = blockIdx.x * blockDim.x + threadIdx.x;
  if (i < N_NODES) offs[i] += bsum[i >> 8];
}

__global__ void scatter_edges(const void* __restrict__ ei, const int* __restrict__ offs,
                              int* __restrict__ tmp, int* __restrict__ ssrc,
                              const int* __restrict__ flags) {
  int e = blockIdx.x * blockDim.x + threadIdx.x;
  int f = flags[1];
  if (e < N_EDGES) {
    int src = load_id_clamped(ei, e, f, N_NODES);
    int dst = load_id_clamped(ei, N_EDGES + e, f, N_NODES);
    int pos = offs[dst] + atomicAdd(&tmp[dst], 1);
    ssrc[pos] = src;
  }
}

// ---------------- fused QKVS GEMM v2: LDS-shared B ----------------
// X raw: fp32 or bf16 per xf. WT*: LDS-image layout [k/8][128][8] bf16.
// Block = 256 thr = 4 waves, 64 rows. Wave (rt = wid&1, ch = wid>>1):
// rows rowbase+rt*32..+32 (2 MFMA row-tiles), cols ch*64..+64 (4 col-frags).
// Per mat: stage B to LDS (linear copy), sync, 32 MFMAs vs 16 ds_read_b128.
// So may alias X (in-place per-row): A-frags register-resident before stores.

template<int KD>
__global__ __launch_bounds__(256)
void gemm_qkvs(const void* X,
               const short* __restrict__ WTq, const short* __restrict__ WTk,
               const short* __restrict__ WTv, const short* __restrict__ WTs,
               const void* __restrict__ bq, const void* __restrict__ bk,
               const void* __restrict__ bv, const void* __restrict__ bs,
               short* Qo, short* Ko, short* Vo, short* So,
               const int* __restrict__ flags, int xf_is_flag, int n)
{
  constexpr int KT = KD / 32;          // MFMA k-steps
  constexpr int CHUNKS = KD * 16;      // 16B chunks of one weight matrix
  __shared__ short smem[KD * 128];     // one matrix: KD=128 -> 32 KB, KD=64 -> 16 KB

  const int f    = flags[0];
  const int xf   = xf_is_flag ? f : 0; // layer-2 input is always bf16
  const int tid  = threadIdx.x;
  const int wid  = tid >> 6;
  const int lane = tid & 63;
  const int quad = lane >> 4;
  const int mm   = lane & 15;
  const int rt   = wid & 1;            // row-tile half (32 rows)
  const int ch   = wid >> 1;           // col half (64 cols)
  const int rowbase = blockIdx.x * 64 + rt * 32;

  // A fragments for 2 row-tiles (rows rowbase + t*16 + mm)
  s16x8 afrag[2][KT];
  #pragma unroll
  for (int t = 0; t < 2; ++t) {
    const int arow = rowbase + t * 16 + mm;
    if (arow < n) {
      if (xf) {
        const float* xp = (const float*)X + (size_t)arow * KD;
        #pragma unroll
        for (int kt = 0; kt < KT; ++kt) {
          const float4* p = (const float4*)(xp + kt * 32 + quad * 8);
          float4 a = p[0], b = p[1];
          s16x8 fr;
          fr[0] = f2bfs(a.x); fr[1] = f2bfs(a.y); fr[2] = f2bfs(a.z); fr[3] = f2bfs(a.w);
          fr[4] = f2bfs(b.x); fr[5] = f2bfs(b.y); fr[6] = f2bfs(b.z); fr[7] = f2bfs(b.w);
          afrag[t][kt] = fr;
        }
      } else {
        const short* xp = (const short*)X + (size_t)arow * KD;
        #pragma unroll
        for (int kt = 0; kt < KT; ++kt)
          afrag[t][kt] = *(const s16x8*)(xp + kt * 32 + quad * 8);
      }
    } else {
      #pragma unroll
      for (int kt = 0; kt < KT; ++kt)
        afrag[t][kt] = (s16x8){0,0,0,0,0,0,0,0};
    }
  }

  const short* wts[4] = {WTq, WTk, WTv, WTs};
  const void* bias[4] = {bq, bk, bv, bs};
  short* outs[4] = {Qo, Ko, Vo, So};

  #pragma unroll
  for (int mat = 0; mat < 4; ++mat) {
    if (mat > 0) __syncthreads();        // all waves done reading previous mat
    // stage matrix into LDS: pure linear copy (coalesced, conflict-free)
    {
      const uint4* src = (const uint4*)wts[mat];
      uint4* dst = (uint4*)smem;
      #pragma unroll
      for (int i = 0; i < CHUNKS / 256; ++i)
        dst[tid + i * 256] = src[tid + i * 256];
    }
    __syncthreads();

    f32x4 acc[4][2];
    #pragma unroll
    for (int c4 = 0; c4 < 4; ++c4) {
      float b = load_f(bias[mat], ch * 64 + c4 * 16 + mm, f);
      f32x4 av = {b, b, b, b};
      acc[c4][0] = av; acc[c4][1] = av;
    }
    #pragma unroll
    for (int kt = 0; kt < KT; ++kt) {
      #pragma unroll
      for (int c4 = 0; c4 < 4; ++c4) {
        s16x8 bfrag = *(const s16x8*)(smem + ((((kt * 4 + quad) << 7) + ch * 64 + c4 * 16 + mm) << 3));
        acc[c4][0] = __builtin_amdgcn_mfma_f32_16x16x32_bf16(afrag[0][kt], bfrag, acc[c4][0], 0, 0, 0);
        acc[c4][1] = __builtin_amdgcn_mfma_f32_16x16x32_bf16(afrag[1][kt], bfrag, acc[c4][1], 0, 0, 0);
      }
    }
    short* O = outs[mat];
    #pragma unroll
    for (int c4 = 0; c4 < 4; ++c4) {
      const int col = ch * 64 + c4 * 16 + mm;
      #pragma unroll
      for (int t = 0; t < 2; ++t) {
        #pragma unroll
        for (int r = 0; r < 4; ++r) {
          int row = rowbase + t * 16 + quad * 4 + r;
          if (row < n)
            ((__hip_bfloat16*)O)[(size_t)row * 128 + col] = __float2bfloat16(acc[c4][t][r]);
        }
      }
    }
  }
}

// ---------------- attention v3 ----------------
// 1 wave per dst (4 dsts/block). Within a wave: 4 edge slots x 16 channel-lanes.
// No-max softmax (logits tiny), exp2 domain, register double-buffered K/V gather.
// H may alias S (in-place per dst row).

__global__ __launch_bounds__(256)
void attn_kernel(const unsigned short* __restrict__ Q, const unsigned short* __restrict__ K,
                 const unsigned short* __restrict__ V, const unsigned short* S,
                 const int* __restrict__ offs, const int* __restrict__ ssrc,
                 unsigned short* H)
{
  const int dst = blockIdx.x * 4 + (threadIdx.x >> 6);
  if (dst >= N_NODES) return;               // wave-uniform
  const int lane = threadIdx.x & 63;
  const int sub  = lane >> 4;
  const int cl   = lane & 15;

  const float qs = 0.17677669529663687f * 1.4426950408889634f;
  uint4 qw = *(const uint4*)(Q + (size_t)dst * 128 + cl * 8);
  float q[8], a[8];
  #pragma unroll
  for (int i = 0; i < 4; ++i) {
    unsigned w = ((unsigned*)&qw)[i];
    q[2 * i]     = bfbits2f(w & 0xffffu) * qs;
    q[2 * i + 1] = bfhi2f(w) * qs;
    a[2 * i] = 0.f; a[2 * i + 1] = 0.f;
  }
  float s = 0.f;

  const int e0 = offs[dst], e1 = offs[dst + 1];
  const int iters = (e1 - e0 + 3) >> 2;

  if (iters > 0) {
    int e = e0 + sub;
    bool have = (e < e1);
    int src = have ? ssrc[e] : ssrc[e0];
    float ph = have ? 1.f : 0.f;
    uint4 kw = *(const uint4*)(K + (size_t)src * 128 + cl * 8);
    uint4 vw = *(const uint4*)(V + (size_t)src * 128 + cl * 8);

    for (int it = 0; it < iters; ++it) {
      uint4 kwn, vwn;
      int en = e + 4;
      bool haven = (en < e1);
      float phn = haven ? 1.f : 0.f;
      if (it + 1 < iters) {                 // wave-uniform branch
        int srcn = haven ? ssrc[en] : ssrc[e0];
        kwn = *(const uint4*)(K + (size_t)srcn * 128 + cl * 8);
        vwn = *(const uint4*)(V + (size_t)srcn * 128 + cl * 8);
      } else {
        kwn = kw; vwn = vw;
      }
      float d = 0.f;
      #pragma unroll
      for (int i = 0; i < 4; ++i) {
        unsigned w = ((unsigned*)&kw)[i];
        d += q[2 * i]     * bfbits2f(w & 0xffffu);
        d += q[2 * i + 1] * bfhi2f(w);
      }
      d += __shfl_xor(d, 1, 64);
      d += __shfl_xor(d, 2, 64);
      float p = exp2f(d) * ph;
      s += p;
      #pragma unroll
      for (int i = 0; i < 4; ++i) {
        unsigned w = ((unsigned*)&vw)[i];
        a[2 * i]     += p * bfbits2f(w & 0xffffu);
        a[2 * i + 1] += p * bfhi2f(w);
      }
      kw = kwn; vw = vwn; e = en; ph = phn;
    }
  }

  s += __shfl_xor(s, 16, 64);
  s += __shfl_xor(s, 32, 64);
  #pragma unroll
  for (int i = 0; i < 8; ++i) {
    a[i] += __shfl_xor(a[i], 16, 64);
    a[i] += __shfl_xor(a[i], 32, 64);
  }
  const float inv = (s > 0.f) ? (1.0f / s) : 0.f;

  if (sub == 0) {
    uint4 sw = *(const uint4*)(S + (size_t)dst * 128 + cl * 8);
    uint4 ow;
    #pragma unroll
    for (int i = 0; i < 4; ++i) {
      unsigned w = ((unsigned*)&sw)[i];
      float o0 = fmaxf(a[2 * i] * inv     + bfbits2f(w & 0xffffu), 0.f);
      float o1 = fmaxf(a[2 * i + 1] * inv + bfhi2f(w), 0.f);
      ((unsigned*)&ow)[i] = (unsigned)f2bfu(o0) | ((unsigned)f2bfu(o1) << 16);
    }
    *(uint4*)(H + (size_t)dst * 128 + cl * 8) = ow;
  }
}

// ---------------- pooling + final linear ----------------

__device__ __forceinline__ int lower_bound_b(const void* b, int n, long long val, int i64) {
  int lo = 0, hi = n;
  while (lo < hi) { int mid = (lo + hi) >> 1; if (load_b(b, mid, i64) < val) lo = mid + 1; else hi = mid; }
  return lo;
}

__global__ __launch_bounds__(128)
void pool_partial(const __hip_bfloat16* __restrict__ H, const void* __restrict__ batch,
                  float* __restrict__ pooled, const int* __restrict__ flags)
{
  const int g = blockIdx.x >> 4, p = blockIdx.x & 15, t = threadIdx.x;
  const int i64 = flags[1];
  const int s = lower_bound_b(batch, N_NODES, g, i64);
  const int e = lower_bound_b(batch, N_NODES, g + 1, i64);
  const int len = e - s;
  if (len <= 0) return;
  const int chunk = (len + 15) >> 4;
  const int a = s + p * chunk;
  const int b = min(a + chunk, e);
  if (a >= b) return;
  float sum = 0.f;
  for (int i = a; i < b; ++i) sum += bf2f(H[(size_t)i * 128 + t]);
  atomicAdd(&pooled[g * 128 + t], sum);
}

__global__ __launch_bounds__(128)
void pool_final(const float* __restrict__ pooled, const void* __restrict__ batch,
                const void* __restrict__ Wl, const void* __restrict__ bl,
                void* out, const int* __restrict__ flags)
{
  const int g = blockIdx.x, t = threadIdx.x;
  __shared__ float r0[128], r1[128];
  const int i64 = flags[1], f = flags[0];
  const int s = lower_bound_b(batch, N_NODES, g, i64);
  const int e = lower_bound_b(batch, N_NODES, g + 1, i64);
  const float inv = 1.0f / (float)max(e - s, 1);
  const float pc = pooled[g * 128 + t] * inv;
  r0[t] = pc * load_f(Wl, t * 2 + 0, f);
  r1[t] = pc * load_f(Wl, t * 2 + 1, f);
  __syncthreads();
  for (int o = 64; o > 0; o >>= 1) {
    if (t < o) { r0[t] += r0[t + o]; r1[t] += r1[t + o]; }
    __syncthreads();
  }
  if (t == 0) {
    float o0 = r0[0] + load_f(bl, 0, f);
    float o1 = r1[0] + load_f(bl, 1, f);
    if (f) {
      ((float*)out)[g * 2 + 0] = o0;
      ((float*)out)[g * 2 + 1] = o1;
    } else {
      ((__hip_bfloat16*)out)[g * 2 + 0] = __float2bfloat16(o0);
      ((__hip_bfloat16*)out)[g * 2 + 1] = __float2bfloat16(o1);
    }
  }
}

// ---------------- launch ----------------

extern "C" void kernel_launch(void* const* d_in, const int* in_sizes, int n_in,
                              void* d_out, int out_size, void* d_ws, size_t ws_size,
                              hipStream_t stream) {
  uintptr_t base = (uintptr_t)d_ws;
  auto take = [&](size_t bytes) -> uintptr_t {
    uintptr_t p = base;
    base += (bytes + 255) & ~(size_t)255;
    return p;
  };

  int*   flags  = (int*)take(2 * 4);
  int*   cnt    = (int*)take((size_t)N_NODES * 4);
  int*   tmp    = (int*)take((size_t)N_NODES * 4);
  int*   offs   = (int*)take((size_t)(N_NODES + 1) * 4);
  int*   bsum   = (int*)take((size_t)NB_SCAN * 4);
  int*   ssrc   = (int*)take((size_t)N_EDGES * 4);
  short* Qb     = (short*)take((size_t)N_NODES * 128 * 2);
  short* Kb     = (short*)take((size_t)N_NODES * 128 * 2);
  short* Vb     = (short*)take((size_t)N_NODES * 128 * 2);
  short* Sb     = (short*)take((size_t)N_NODES * 128 * 2);   // also H and layer-2 X (in-place)
  short* wt1q   = (short*)take((size_t)IN_CH * 128 * 2);
  short* wt1k   = (short*)take((size_t)IN_CH * 128 * 2);
  short* wt1v   = (short*)take((size_t)IN_CH * 128 * 2);
  short* wt1s   = (short*)take((size_t)IN_CH * 128 * 2);
  short* wt2q   = (short*)take((size_t)HID_CH * 128 * 2);
  short* wt2k   = (short*)take((size_t)HID_CH * 128 * 2);
  short* wt2v   = (short*)take((size_t)HID_CH * 128 * 2);
  short* wt2s   = (short*)take((size_t)HID_CH * 128 * 2);
  float* pooled = (float*)take((size_t)N_GRAPHS * 128 * 4);

  detect_dtypes<<<1, 256, 0, stream>>>((const unsigned*)d_in[0], (const unsigned*)d_in[1], flags);

  conv_wt<<<(4 * 64 * 128 + 4 * 128 * 128 + 255) / 256, 256, 0, stream>>>(
      d_in[3], d_in[5], d_in[7], d_in[9], d_in[11], d_in[13], d_in[15], d_in[17],
      (__hip_bfloat16*)wt1q, (__hip_bfloat16*)wt1k, (__hip_bfloat16*)wt1v, (__hip_bfloat16*)wt1s,
      (__hip_bfloat16*)wt2q, (__hip_bfloat16*)wt2k, (__hip_bfloat16*)wt2v, (__hip_bfloat16*)wt2s,
      flags);

  init_ws<<<(N_NODES + 255) / 256, 256, 0, stream>>>(cnt, tmp, pooled);
  count_deg<<<(N_EDGES + 255) / 256, 256, 0, stream>>>(d_in[1], cnt, flags);
  scan1<<<NB_SCAN, 256, 0, stream>>>(cnt, offs, bsum);
  scan2<<<1, 256, 0, stream>>>(bsum, offs);
  scan3<<<NB_SCAN, 256, 0, stream>>>(offs, bsum);
  scatter_edges<<<(N_EDGES + 255) / 256, 256, 0, stream>>>(d_in[1], offs, tmp, ssrc, flags);

  const int gemm_grid = (N_NODES + 63) / 64;
  const int attn_grid = (N_NODES + 3) / 4;

  // ---- layer 1 (raw x input, dtype per flags) ----
  gemm_qkvs<IN_CH><<<gemm_grid, 256, 0, stream>>>(
      d_in[0], wt1q, wt1k, wt1v, wt1s,
      d_in[4], d_in[6], d_in[8], d_in[10],
      Qb, Kb, Vb, Sb, flags, 1, N_NODES);
  attn_kernel<<<attn_grid, 256, 0, stream>>>(
      (const unsigned short*)Qb, (const unsigned short*)Kb, (const unsigned short*)Vb,
      (const unsigned short*)Sb, offs, ssrc, (unsigned short*)Sb);

  // ---- layer 2 (X = Sb bf16, S written in place into Sb) ----
  gemm_qkvs<HID_CH><<<gemm_grid, 256, 0, stream>>>(
      Sb, wt2q, wt2k, wt2v, wt2s,
      d_in[12], d_in[14], d_in[16], d_in[18],
      Qb, Kb, Vb, Sb, flags, 0, N_NODES);
  attn_kernel<<<attn_grid, 256, 0, stream>>>(
      (const unsigned short*)Qb, (const unsigned short*)Kb, (const unsigned short*)Vb,
      (const unsigned short*)Sb, offs, ssrc, (unsigned short*)Sb);

  // ---- pool + linear ----
  pool_partial<<<N_GRAPHS * 16, 128, 0, stream>>>(
      (const __hip_bfloat16*)Sb, d_in[2], pooled, flags);
  pool_final<<<N_GRAPHS, 128, 0, stream>>>(pooled, d_in[2], d_in[19], d_in[20], d_out, flags);
}